// Round 1
// baseline (1006.004 us; speedup 1.0000x reference)
//
#include <hip/hip_runtime.h>
#include <math.h>

// Problem dims
#define C_    192
#define C3    576
#define S_    65536          // 256*256
#define IMGW  256
#define NHEAD 8
#define HSLAB 1572864L       // 24*65536 elements per head slab
#define CN    8192           // per-head row length (S_/8)
#define KSLABS 8
#define KSLAB  1024

typedef unsigned short u16;
typedef unsigned int   u32;

__device__ __forceinline__ float bf2f(u16 h) {
  u32 u = ((u32)h) << 16;
  return __uint_as_float(u);
}
__device__ __forceinline__ u16 f2bf(float f) {
  u32 u = __float_as_uint(f);
  u32 r = (u + 0x7fffu + ((u >> 16) & 1u)) >> 16;
  return (u16)r;
}

// ---- vector load helpers (convert to fp32) ----
__device__ __forceinline__ void load8(const float* p, float* v) {
  float4 x = *(const float4*)p;
  float4 y = *(const float4*)(p + 4);
  v[0]=x.x; v[1]=x.y; v[2]=x.z; v[3]=x.w;
  v[4]=y.x; v[5]=y.y; v[6]=y.z; v[7]=y.w;
}
__device__ __forceinline__ void load8(const u16* p, float* v) {
  uint4 u = *(const uint4*)p;
  v[0]=bf2f((u16)(u.x & 0xffff)); v[1]=bf2f((u16)(u.x >> 16));
  v[2]=bf2f((u16)(u.y & 0xffff)); v[3]=bf2f((u16)(u.y >> 16));
  v[4]=bf2f((u16)(u.z & 0xffff)); v[5]=bf2f((u16)(u.z >> 16));
  v[6]=bf2f((u16)(u.w & 0xffff)); v[7]=bf2f((u16)(u.w >> 16));
}
__device__ __forceinline__ void store4(float* p, const float* v) {
  *(float4*)p = make_float4(v[0], v[1], v[2], v[3]);
}
__device__ __forceinline__ void store4(u16* p, const float* v) {
  ushort4 s;
  s.x = f2bf(v[0]); s.y = f2bf(v[1]); s.z = f2bf(v[2]); s.w = f2bf(v[3]);
  *(ushort4*)p = s;
}

// ---- generic NN GEMM: C[m,n] = sum_k A[m,k]*B[k,n]; lda==K ----
// 64x128 tile, 256 threads, 4x(4+4) microtile, BK=16
template<typename TB, typename TC>
__global__ __launch_bounds__(256)
void gemm_nn_kernel(const float* __restrict__ A, const TB* __restrict__ B,
                    TC* __restrict__ C,
                    int K, long strideA, long sBo, long sBi, int zinner,
                    long strideC, int ldb, int ldc)
{
  __shared__ float As[16][64];
  __shared__ float Bs[16][132];
  const int tid = threadIdx.x;
  const int bx = blockIdx.x, by = blockIdx.y, bz = blockIdx.z;
  const float* Ab = A + (long)bz * strideA;
  const TB* Bb = B + (long)(bz / zinner) * sBo + (long)(bz % zinner) * sBi;
  TC* Cb = C + (long)bz * strideC;
  const int m0 = by * 64, n0 = bx * 128;
  const int tx = tid & 15, ty = tid >> 4;
  const int la_m = tid >> 2;
  const int la_k = (tid & 3) << 2;
  const int lb_k = tid >> 4;
  const int lb_n = (tid & 15) << 3;

  float acc[4][8];
#pragma unroll
  for (int i = 0; i < 4; i++)
#pragma unroll
    for (int j = 0; j < 8; j++) acc[i][j] = 0.f;

  for (int k0 = 0; k0 < K; k0 += 16) {
    __syncthreads();
    float4 av = *(const float4*)(Ab + (long)(m0 + la_m) * K + (k0 + la_k));
    As[la_k + 0][la_m] = av.x;
    As[la_k + 1][la_m] = av.y;
    As[la_k + 2][la_m] = av.z;
    As[la_k + 3][la_m] = av.w;
    float bv[8];
    load8(Bb + (long)(k0 + lb_k) * ldb + (n0 + lb_n), bv);
#pragma unroll
    for (int j = 0; j < 8; j++) Bs[lb_k][lb_n + j] = bv[j];
    __syncthreads();
#pragma unroll
    for (int kk = 0; kk < 16; kk++) {
      float a[4], b[8];
#pragma unroll
      for (int i = 0; i < 4; i++) a[i] = As[kk][ty * 4 + i];
#pragma unroll
      for (int j = 0; j < 4; j++) {
        b[j]     = Bs[kk][tx * 4 + j];
        b[4 + j] = Bs[kk][64 + tx * 4 + j];
      }
#pragma unroll
      for (int i = 0; i < 4; i++)
#pragma unroll
        for (int j = 0; j < 8; j++) acc[i][j] = fmaf(a[i], b[j], acc[i][j]);
    }
  }
#pragma unroll
  for (int i = 0; i < 4; i++) {
    TC* cp = Cb + (long)(m0 + ty * 4 + i) * ldc + n0;
    store4(cp + tx * 4,      &acc[i][0]);
    store4(cp + 64 + tx * 4, &acc[i][4]);
  }
}

// ---- depthwise 3x3, SAME padding, per-channel weights ----
// one block = one (b*channel, 16-row tile); 256 threads = 256 columns
__global__ __launch_bounds__(256)
void dwconv_kernel(const u16* __restrict__ in, const float* __restrict__ w9s,
                   u16* __restrict__ out)
{
  const int bo = blockIdx.x >> 4;       // 0..1151  (b*576 + o)
  const int rt = blockIdx.x & 15;       // row tile
  const int o  = bo % C3;
  const u16* ip = in + (long)bo * S_;
  u16* op = out + (long)bo * S_;
  float w[9];
#pragma unroll
  for (int i = 0; i < 9; i++) w[i] = w9s[o * 9 + i];

  __shared__ float tile[18 * 256];
  const int t = threadIdx.x;
  for (int vi = t; vi < 1152; vi += 256) {   // 1152 ushort4 chunks = 18*256 elems
    int row = vi >> 6;
    int col = (vi & 63) << 2;
    int g = rt * 16 - 1 + row;
    if (g >= 0 && g < 256) {
      ushort4 u = *(const ushort4*)(ip + g * 256 + col);
      tile[row * 256 + col + 0] = bf2f(u.x);
      tile[row * 256 + col + 1] = bf2f(u.y);
      tile[row * 256 + col + 2] = bf2f(u.z);
      tile[row * 256 + col + 3] = bf2f(u.w);
    } else {
      tile[row * 256 + col + 0] = 0.f;
      tile[row * 256 + col + 1] = 0.f;
      tile[row * 256 + col + 2] = 0.f;
      tile[row * 256 + col + 3] = 0.f;
    }
  }
  __syncthreads();
  const int col = t;
  const bool cl = (col > 0), cr = (col < 255);
#pragma unroll 4
  for (int ro = 0; ro < 16; ro++) {
    const float* r0 = &tile[(ro + 0) * 256 + col];
    const float* r1 = &tile[(ro + 1) * 256 + col];
    const float* r2 = &tile[(ro + 2) * 256 + col];
    float acc = r0[0] * w[1] + r1[0] * w[4] + r2[0] * w[7];
    if (cl) acc += r0[-1] * w[0] + r1[-1] * w[3] + r2[-1] * w[6];
    if (cr) acc += r0[1] * w[2] + r1[1] * w[5] + r2[1] * w[8];
    op[(rt * 16 + ro) * 256 + col] = f2bf(acc);
  }
}

// ---- L2 normalize rows of 8192 (q and k regions), in place, bf16 ----
__global__ __launch_bounds__(256)
void l2norm_kernel(u16* __restrict__ qkvc)
{
  long base = (long)blockIdx.z * ((long)C3 * S_) + (long)blockIdx.y * ((long)C_ * S_);
  u16* p = qkvc + base + (long)blockIdx.x * CN;
  const int t = threadIdx.x;
  float v[32];
  float ss = 0.f;
#pragma unroll
  for (int i = 0; i < 8; i++) {
    ushort4 u = *(const ushort4*)(p + (i * 256 + t) * 4);
    float a = bf2f(u.x), b = bf2f(u.y), c = bf2f(u.z), d = bf2f(u.w);
    v[i * 4 + 0] = a; v[i * 4 + 1] = b; v[i * 4 + 2] = c; v[i * 4 + 3] = d;
    ss += a * a + b * b + c * c + d * d;
  }
#pragma unroll
  for (int o = 32; o >= 1; o >>= 1) ss += __shfl_xor(ss, o);
  __shared__ float red[4];
  if ((t & 63) == 0) red[t >> 6] = ss;
  __syncthreads();
  ss = red[0] + red[1] + red[2] + red[3];
  float scale = 1.f / fmaxf(sqrtf(ss), 1e-12f);
#pragma unroll
  for (int i = 0; i < 8; i++) {
    ushort4 u;
    u.x = f2bf(v[i * 4 + 0] * scale);
    u.y = f2bf(v[i * 4 + 1] * scale);
    u.z = f2bf(v[i * 4 + 2] * scale);
    u.w = f2bf(v[i * 4 + 3] * scale);
    *(ushort4*)(p + (i * 256 + t) * 4) = u;
  }
}

// ---- QK^T partials: per (b,h,kslab) 64x64 tiles; NT GEMM K=1024 slab ----
__global__ __launch_bounds__(256)
void gemm_qk_kernel(const u16* __restrict__ qkvc, float* __restrict__ part)
{
  const int bz = blockIdx.z;
  const int bh = bz / KSLABS, ks = bz % KSLABS;
  const int b = bh / NHEAD, h = bh % NHEAD;
  const u16* Q  = qkvc + (long)b * ((long)C3 * S_) + (long)h * HSLAB;
  const u16* Kp = Q + (long)C_ * S_;
  float* P = part + ((long)ks * 16 + bh) * (192L * 192L);
  __shared__ float Qs[16][65];
  __shared__ float Ks[16][65];
  const int tid = threadIdx.x;
  const int tx = tid & 15, ty = tid >> 4;
  const int m0 = blockIdx.y * 64, n0 = blockIdx.x * 64;
  const int lr = tid >> 2;
  const int lk = (tid & 3) << 2;
  float acc[4][4];
#pragma unroll
  for (int i = 0; i < 4; i++)
#pragma unroll
    for (int j = 0; j < 4; j++) acc[i][j] = 0.f;

  const int kbeg = ks * KSLAB;
  for (int k0 = kbeg; k0 < kbeg + KSLAB; k0 += 16) {
    __syncthreads();
    {
      ushort4 q4 = *(const ushort4*)(Q + (long)(m0 + lr) * CN + (k0 + lk));
      Qs[lk + 0][lr] = bf2f(q4.x);
      Qs[lk + 1][lr] = bf2f(q4.y);
      Qs[lk + 2][lr] = bf2f(q4.z);
      Qs[lk + 3][lr] = bf2f(q4.w);
      ushort4 k4 = *(const ushort4*)(Kp + (long)(n0 + lr) * CN + (k0 + lk));
      Ks[lk + 0][lr] = bf2f(k4.x);
      Ks[lk + 1][lr] = bf2f(k4.y);
      Ks[lk + 2][lr] = bf2f(k4.z);
      Ks[lk + 3][lr] = bf2f(k4.w);
    }
    __syncthreads();
#pragma unroll
    for (int kk = 0; kk < 16; kk++) {
      float a[4], bb[4];
#pragma unroll
      for (int i = 0; i < 4; i++) a[i] = Qs[kk][ty * 4 + i];
#pragma unroll
      for (int j = 0; j < 4; j++) bb[j] = Ks[kk][tx * 4 + j];
#pragma unroll
      for (int i = 0; i < 4; i++)
#pragma unroll
        for (int j = 0; j < 4; j++) acc[i][j] = fmaf(a[i], bb[j], acc[i][j]);
    }
  }
#pragma unroll
  for (int i = 0; i < 4; i++)
    *(float4*)(P + (long)(m0 + ty * 4 + i) * 192 + n0 + tx * 4) =
        make_float4(acc[i][0], acc[i][1], acc[i][2], acc[i][3]);
}

// ---- reduce 8 partial slabs + temperature + softmax over 192 cols ----
__global__ __launch_bounds__(64)
void softmax_kernel(const float* __restrict__ part, const float* __restrict__ temp,
                    float* __restrict__ attn)
{
  const int row_g = blockIdx.x;             // 0..3071
  const int bh = row_g / 192, r = row_g % 192;
  const int h = bh % NHEAD;
  const int t = threadIdx.x;
  const float tp = temp[h];
  float l[3];
#pragma unroll
  for (int j = 0; j < 3; j++) {
    int col = t + j * 64;
    float s = 0.f;
#pragma unroll
    for (int ks = 0; ks < 8; ks++)
      s += part[((long)ks * 16 + bh) * 36864L + (long)r * 192 + col];
    l[j] = s * tp;
  }
  float mx = fmaxf(l[0], fmaxf(l[1], l[2]));
#pragma unroll
  for (int o = 32; o >= 1; o >>= 1) mx = fmaxf(mx, __shfl_xor(mx, o));
  float e[3], sum = 0.f;
#pragma unroll
  for (int j = 0; j < 3; j++) { e[j] = expf(l[j] - mx); sum += e[j]; }
#pragma unroll
  for (int o = 32; o >= 1; o >>= 1) sum += __shfl_xor(sum, o);
  float inv = 1.f / sum;
  float* ap = attn + (long)bh * 36864L + (long)r * 192;
#pragma unroll
  for (int j = 0; j < 3; j++) ap[t + j * 64] = e[j] * inv;
}

extern "C" void kernel_launch(void* const* d_in, const int* in_sizes, int n_in,
                              void* d_out, int out_size, void* d_ws, size_t ws_size,
                              hipStream_t stream)
{
  const float* x      = (const float*)d_in[0];
  const float* qkv_w  = (const float*)d_in[1];
  const float* dw_w   = (const float*)d_in[2];
  const float* proj_w = (const float*)d_in[3];
  const float* temp   = (const float*)d_in[4];
  float* out = (float*)d_out;

  // workspace layout (bytes); total needed ~323 MB
  char* ws = (char*)d_ws;
  u16*   qkv      = (u16*)(ws + 0);            // 150,994,944 B (2*576*65536 bf16)
  u16*   qkvc     = (u16*)(ws + 150994944);    // 150,994,944 B
  float* part     = (float*)(ws + 301989888);  // 18,874,368 B (8*16*192*192 f32)
  float* attn     = (float*)(ws + 320864256);  //  2,359,296 B (16*192*192 f32)
  u16*   attn_out = (u16*)(ws + 0);            // reuse qkv region (50,331,648 B)

  // 1) qkv = qkv_w @ x   (M=576, N=65536, K=192, batch 2)
  gemm_nn_kernel<float, u16><<<dim3(512, 9, 2), 256, 0, stream>>>(
      qkv_w, x, qkv, 192,
      0L, 12582912L, 0L, 1, 37748736L, 65536, 65536);

  // 2) depthwise 3x3
  dwconv_kernel<<<dim3(1152 * 16), 256, 0, stream>>>(qkv, dw_w, qkvc);

  // 3) l2norm rows of q and k regions (in place)
  l2norm_kernel<<<dim3(1536, 2, 2), 256, 0, stream>>>(qkvc);

  // 4) attn partials = Qn @ Kn^T per (b,h), 8 k-slabs
  gemm_qk_kernel<<<dim3(3, 3, 16 * KSLABS), 256, 0, stream>>>(qkvc, part);

  // 5) reduce + temperature + softmax
  softmax_kernel<<<dim3(3072), 64, 0, stream>>>(part, temp, attn);

  // 6) attn_out = attn @ V   (M=192, N=8192, K=192, 16 matrices)
  gemm_nn_kernel<u16, u16><<<dim3(64, 3, 16), 256, 0, stream>>>(
      attn, qkvc + 384L * 65536L, attn_out, 192,
      36864L, 37748736L, 1572864L, 8, 1572864L, 8192, 8192);

  // 7) out = proj_w @ attn_out  (M=192, N=65536, K=192, batch 2)
  gemm_nn_kernel<u16, float><<<dim3(512, 3, 2), 256, 0, stream>>>(
      proj_w, attn_out, out, 192,
      0L, 12582912L, 0L, 1, 12582912L, 65536, 65536);
}

// Round 4
// 457.685 us; speedup vs baseline: 2.1980x; 2.1980x over previous
//
#include <hip/hip_runtime.h>
#include <math.h>

typedef unsigned short u16;
typedef unsigned int   u32;
typedef short bf16x8 __attribute__((ext_vector_type(8)));
typedef float f32x4  __attribute__((ext_vector_type(4)));

#define MFMA16(a,b,c) __builtin_amdgcn_mfma_f32_16x16x32_bf16((a),(b),(c),0,0,0)

__device__ __forceinline__ float bf2f(u16 h){ u32 u=((u32)h)<<16; return __uint_as_float(u); }
__device__ __forceinline__ u16 f2bf(float f){ u32 u=__float_as_uint(f); return (u16)((u+0x7fffu+((u>>16)&1u))>>16); }

__device__ __forceinline__ void stc(u16* p, float v){ *p = f2bf(v); }
__device__ __forceinline__ void stc(float* p, float v){ *p = v; }
__device__ __forceinline__ void ld4(const float* p, float* v){ float4 x=*(const float4*)p; v[0]=x.x;v[1]=x.y;v[2]=x.z;v[3]=x.w; }
__device__ __forceinline__ void ld4(const u16* p, float* v){ ushort4 x=*(const ushort4*)p; v[0]=bf2f(x.x);v[1]=bf2f(x.y);v[2]=bf2f(x.z);v[3]=bf2f(x.w); }

// ---- fp32 -> bf16 convert (weights) ----
__global__ void cvt_kernel(const float* __restrict__ in, u16* __restrict__ out, int n){
  int i = blockIdx.x*256 + threadIdx.x;
  if (i < n) out[i] = f2bf(in[i]);
}

// ---- tiled transpose: in [z][192][in_pitch] (TIN) -> out [z][cols][192] bf16 ----
template<typename TIN>
__global__ __launch_bounds__(256) void transpose_kernel(
    const TIN* __restrict__ in, u16* __restrict__ out,
    long in_hi, long in_lo, long out_slab, int in_pitch)
{
  __shared__ float tile[64][65];
  const int t = threadIdx.x;
  const int z = blockIdx.z;
  const TIN* ip = in + (long)(z>>3)*in_hi + (long)(z&7)*in_lo;
  u16* op = out + (long)z*out_slab;
  const int s0 = blockIdx.x*64, c0 = blockIdx.y*64;
  const int rl = t>>4, cc = (t&15)*4;
#pragma unroll
  for (int rr=0; rr<4; rr++){
    int row = rr*16 + rl;
    float v[4];
    ld4(ip + (long)(c0+row)*in_pitch + s0 + cc, v);
    tile[row][cc+0]=v[0]; tile[row][cc+1]=v[1]; tile[row][cc+2]=v[2]; tile[row][cc+3]=v[3];
  }
  __syncthreads();
#pragma unroll
  for (int wr=0; wr<4; wr++){
    int sl = wr*16 + rl;
    ushort4 s;
    s.x = f2bf(tile[cc+0][sl]); s.y = f2bf(tile[cc+1][sl]);
    s.z = f2bf(tile[cc+2][sl]); s.w = f2bf(tile[cc+3][sl]);
    *(ushort4*)(op + (long)(s0+sl)*192 + c0 + cc) = s;
  }
}

// ---- NT MFMA GEMM: C[m][n] = sum_k A[m][k]*B[n][k]; K=192, lda=ldb=192, ldc=65536
// BM=BN=128, BK=32; 4 waves, wave tile 64x64 (4x4 frags of 16x16x32)
template<typename TC>
__global__ __launch_bounds__(256) void gemm_nt_kernel(
    const u16* __restrict__ A, const u16* __restrict__ B, TC* __restrict__ C,
    int M, long sB, long sC)
{
  __shared__ __align__(16) u16 As[128*32];
  __shared__ __align__(16) u16 Bs[128*32];
  const int t = threadIdx.x, w = t>>6, l = t&63;
  const int mt = blockIdx.x, nt = blockIdx.y, bz = blockIdx.z;
  const int m0 = mt*128, n0 = nt*128;
  const u16* Bb = B + (long)bz*sB + (long)n0*192;
  const int rq = t>>2, qq = (t&3)*8;
  int ar0 = m0 + rq;      if (ar0 >= M) ar0 = M-1;
  int ar1 = m0 + 64 + rq; if (ar1 >= M) ar1 = M-1;
  f32x4 acc[4][4];
#pragma unroll
  for (int i=0;i<4;i++)
#pragma unroll
    for (int j=0;j<4;j++) acc[i][j] = f32x4{0.f,0.f,0.f,0.f};

  for (int k0=0; k0<192; k0+=32){
    uint4 va0 = *(const uint4*)(A + (long)ar0*192 + k0 + qq);
    uint4 va1 = *(const uint4*)(A + (long)ar1*192 + k0 + qq);
    uint4 vb0 = *(const uint4*)(Bb + (long)rq*192 + k0 + qq);
    uint4 vb1 = *(const uint4*)(Bb + (long)(64+rq)*192 + k0 + qq);
    __syncthreads();
    *(uint4*)(As + t*8) = va0;
    *(uint4*)(As + (256+t)*8) = va1;
    *(uint4*)(Bs + t*8) = vb0;
    *(uint4*)(Bs + (256+t)*8) = vb1;
    __syncthreads();
    const u16* ap = As + ((w>>1)*64 + (l&15))*32 + (l>>4)*8;
    const u16* bp = Bs + ((w&1)*64 + (l&15))*32 + (l>>4)*8;
    bf16x8 a[4], b[4];
#pragma unroll
    for (int i=0;i<4;i++){ a[i] = *(const bf16x8*)(ap + i*512); b[i] = *(const bf16x8*)(bp + i*512); }
#pragma unroll
    for (int i=0;i<4;i++)
#pragma unroll
      for (int j=0;j<4;j++) acc[i][j] = MFMA16(a[i], b[j], acc[i][j]);
  }
  const int mw = m0 + (w>>1)*64, nw = n0 + (w&1)*64;
  TC* Cb = C + (long)bz*sC;
#pragma unroll
  for (int i=0;i<4;i++){
#pragma unroll
    for (int r=0;r<4;r++){
      int row = mw + i*16 + (l>>4)*4 + r;
      if (row < M){
        TC* cp = Cb + (long)row*65536 + nw + (l&15);
#pragma unroll
        for (int j=0;j<4;j++) stc(cp + j*16, acc[i][j][r]);
      }
    }
  }
}

// ---- depthwise 3x3 + fused per-(channel, 8192-chunk) sum of squares for l2norm ----
__global__ __launch_bounds__(256) void dwconv_kernel(
    const u16* __restrict__ in, const float* __restrict__ w9s,
    u16* __restrict__ out, float* __restrict__ norms)
{
  const int bo = blockIdx.x >> 4;
  const int rt = blockIdx.x & 15;
  const int o  = bo % 576;
  const u16* ip = in + (long)bo*65536L;
  u16* op = out + (long)bo*65536L;
  float w[9];
#pragma unroll
  for (int i=0;i<9;i++) w[i] = w9s[o*9+i];
  __shared__ float tile[18*256];
  const int t = threadIdx.x;
  for (int vi=t; vi<1152; vi+=256){
    int row = vi>>6, col = (vi&63)<<2;
    int g = rt*16 - 1 + row;
    if (g >= 0 && g < 256){
      ushort4 u = *(const ushort4*)(ip + g*256 + col);
      tile[row*256+col+0]=bf2f(u.x); tile[row*256+col+1]=bf2f(u.y);
      tile[row*256+col+2]=bf2f(u.z); tile[row*256+col+3]=bf2f(u.w);
    } else {
      tile[row*256+col+0]=0.f; tile[row*256+col+1]=0.f;
      tile[row*256+col+2]=0.f; tile[row*256+col+3]=0.f;
    }
  }
  __syncthreads();
  const int col = t;
  const bool cl = (col>0), cr = (col<255);
  float ss = 0.f;
#pragma unroll 4
  for (int ro=0; ro<16; ro++){
    const float* r0 = &tile[(ro+0)*256+col];
    const float* r1 = &tile[(ro+1)*256+col];
    const float* r2 = &tile[(ro+2)*256+col];
    float acc = r0[0]*w[1] + r1[0]*w[4] + r2[0]*w[7];
    if (cl) acc += r0[-1]*w[0] + r1[-1]*w[3] + r2[-1]*w[6];
    if (cr) acc += r0[1]*w[2] + r1[1]*w[5] + r2[1]*w[8];
    op[(rt*16+ro)*256 + col] = f2bf(acc);
    ss += acc*acc;
  }
#pragma unroll
  for (int off=32; off>=1; off>>=1) ss += __shfl_xor(ss, off);
  __shared__ float red[4];
  if ((t&63)==0) red[t>>6] = ss;
  __syncthreads();
  if (t==0 && o < 384){
    atomicAdd(&norms[bo*8 + (rt>>1)], red[0]+red[1]+red[2]+red[3]);
  }
}

// ---- QK^T MFMA, K-split partials: C[m][n] = sum_s Q[m][s]K[n][s] (raw, unnormalized)
// grid (3,3,128): z = bh*8 + slab; BM=BN=64, BK=64, slab=1024
__global__ __launch_bounds__(256) void gemm_qk_kernel(
    const u16* __restrict__ conv, float* __restrict__ part)
{
  __shared__ __align__(16) u16 As[64*64];
  __shared__ __align__(16) u16 Bs[64*64];
  const int t = threadIdx.x, w = t>>6, l = t&63;
  const int mt = blockIdx.x, nt = blockIdx.y, z = blockIdx.z;
  const int bh = z>>3, sl = z&7;
  const int b = bh>>3, h = bh&7;
  const u16* Q  = conv + (long)b*37748736L + (long)h*1572864L;
  const u16* Kp = Q + 12582912L;
  const int m0 = mt*64, n0 = nt*64;
  const int rq = t>>3, qq = (t&7)*8;
  const long qo0 = (long)(m0+rq)*8192 + qq;
  const long qo1 = (long)(m0+32+rq)*8192 + qq;
  const long ko0 = (long)(n0+rq)*8192 + qq;
  const long ko1 = (long)(n0+32+rq)*8192 + qq;
  f32x4 acc[2][2];
#pragma unroll
  for (int i=0;i<2;i++)
#pragma unroll
    for (int j=0;j<2;j++) acc[i][j] = f32x4{0.f,0.f,0.f,0.f};
  const int kbeg = sl*1024;
  for (int k0=kbeg; k0<kbeg+1024; k0+=64){
    uint4 vq0 = *(const uint4*)(Q  + qo0 + k0);
    uint4 vq1 = *(const uint4*)(Q  + qo1 + k0);
    uint4 vk0 = *(const uint4*)(Kp + ko0 + k0);
    uint4 vk1 = *(const uint4*)(Kp + ko1 + k0);
    __syncthreads();
    *(uint4*)(As + t*8) = vq0;
    *(uint4*)(As + (256+t)*8) = vq1;
    *(uint4*)(Bs + t*8) = vk0;
    *(uint4*)(Bs + (256+t)*8) = vk1;
    __syncthreads();
    const u16* ap = As + ((w>>1)*32 + (l&15))*64 + (l>>4)*8;
    const u16* bp = Bs + ((w&1)*32 + (l&15))*64 + (l>>4)*8;
#pragma unroll
    for (int ks=0; ks<2; ks++){
      bf16x8 a0 = *(const bf16x8*)(ap + ks*32);
      bf16x8 a1 = *(const bf16x8*)(ap + 1024 + ks*32);
      bf16x8 b0 = *(const bf16x8*)(bp + ks*32);
      bf16x8 b1 = *(const bf16x8*)(bp + 1024 + ks*32);
      acc[0][0]=MFMA16(a0,b0,acc[0][0]); acc[0][1]=MFMA16(a0,b1,acc[0][1]);
      acc[1][0]=MFMA16(a1,b0,acc[1][0]); acc[1][1]=MFMA16(a1,b1,acc[1][1]);
    }
  }
  float* P = part + (long)z*36864L;
  const int mw = m0 + (w>>1)*32, nw = n0 + (w&1)*32;
#pragma unroll
  for (int i=0;i<2;i++)
#pragma unroll
    for (int j=0;j<2;j++)
#pragma unroll
      for (int r=0;r<4;r++)
        P[(long)(mw + i*16 + (l>>4)*4 + r)*192 + nw + j*16 + (l&15)] = acc[i][j][r];
}

// ---- reduce partials + l2norm scales + temperature + softmax -> attn bf16 ----
__global__ __launch_bounds__(64) void softmax_kernel(
    const float* __restrict__ part, const float* __restrict__ temp,
    const float* __restrict__ norms, u16* __restrict__ attn)
{
  const int rg = blockIdx.x;
  const int bh = rg/192, r = rg - bh*192;
  const int b = bh>>3, h = bh&7;
  const int t = threadIdx.x;
  const float tp = temp[h];
  const float sq = norms[(b*576 + 24*h + (r>>3))*8 + (r&7)];
  const float invq = 1.f/fmaxf(sqrtf(sq), 1e-12f);
  const float* P = part + (long)bh*8L*36864L + (long)r*192;
  float lv[3];
#pragma unroll
  for (int j=0;j<3;j++){
    int col = t + j*64;
    float s = 0.f;
#pragma unroll
    for (int ks=0; ks<8; ks++) s += P[(long)ks*36864L + col];
    float sk = norms[(b*576 + 192 + 24*h + (col>>3))*8 + (col&7)];
    float invk = 1.f/fmaxf(sqrtf(sk), 1e-12f);
    lv[j] = s*invq*invk*tp;
  }
  float mx = fmaxf(lv[0], fmaxf(lv[1], lv[2]));
#pragma unroll
  for (int o=32;o>=1;o>>=1) mx = fmaxf(mx, __shfl_xor(mx, o));
  float e[3], sum = 0.f;
#pragma unroll
  for (int j=0;j<3;j++){ e[j] = expf(lv[j]-mx); sum += e[j]; }
#pragma unroll
  for (int o=32;o>=1;o>>=1) sum += __shfl_xor(sum, o);
  const float inv = 1.f/sum;
  u16* ap = attn + (long)bh*36864L + (long)r*192;
#pragma unroll
  for (int j=0;j<3;j++) ap[t + j*64] = f2bf(e[j]*inv);
}

// ---- attn@V: D[n][c'] = sum_d VT[n][d]*attn[c'][d]; bounce epilogue -> out_sc[s][C]
// grid (64, 2, 16)
__global__ __launch_bounds__(256) void gemm_av_kernel(
    const u16* __restrict__ VT, const u16* __restrict__ attn, u16* __restrict__ out_sc)
{
  __shared__ __align__(16) char smem[69632];
  u16* As = (u16*)smem;
  u16* Bs = (u16*)(smem + 8192);
  const int t = threadIdx.x, w = t>>6, l = t&63;
  const int mt = blockIdx.x, nt = blockIdx.y, bh = blockIdx.z;
  const int b = bh>>3, h = bh&7;
  const u16* Av = VT + (long)bh*1572864L;
  const u16* Bt = attn + (long)bh*36864L;
  const int m0 = mt*128, n0 = nt*128;
  const int rq = t>>2, qq = (t&3)*8;
  int br0 = n0 + rq;      if (br0 > 191) br0 = 191;
  int br1 = n0 + 64 + rq; if (br1 > 191) br1 = 191;
  f32x4 acc[4][4];
#pragma unroll
  for (int i=0;i<4;i++)
#pragma unroll
    for (int j=0;j<4;j++) acc[i][j] = f32x4{0.f,0.f,0.f,0.f};
  for (int k0=0; k0<192; k0+=32){
    uint4 va0 = *(const uint4*)(Av + (long)(m0+rq)*192 + k0 + qq);
    uint4 va1 = *(const uint4*)(Av + (long)(m0+64+rq)*192 + k0 + qq);
    uint4 vb0 = *(const uint4*)(Bt + (long)br0*192 + k0 + qq);
    uint4 vb1 = *(const uint4*)(Bt + (long)br1*192 + k0 + qq);
    __syncthreads();
    *(uint4*)(As + t*8) = va0;
    *(uint4*)(As + (256+t)*8) = va1;
    *(uint4*)(Bs + t*8) = vb0;
    *(uint4*)(Bs + (256+t)*8) = vb1;
    __syncthreads();
    const u16* ap = As + ((w>>1)*64 + (l&15))*32 + (l>>4)*8;
    const u16* bp = Bs + ((w&1)*64 + (l&15))*32 + (l>>4)*8;
    bf16x8 a[4], bb[4];
#pragma unroll
    for (int i=0;i<4;i++){ a[i] = *(const bf16x8*)(ap + i*512); bb[i] = *(const bf16x8*)(bp + i*512); }
#pragma unroll
    for (int i=0;i<4;i++)
#pragma unroll
      for (int j=0;j<4;j++) acc[i][j] = MFMA16(a[i], bb[j], acc[i][j]);
  }
  __syncthreads();                 // everyone done reading As/Bs
  float* wb = (float*)smem + w*4352;   // per-wave 64x68 f32 bounce
#pragma unroll
  for (int i=0;i<4;i++)
#pragma unroll
    for (int j=0;j<4;j++)
#pragma unroll
      for (int r=0;r<4;r++)
        wb[(i*16 + (l>>4)*4 + r)*68 + j*16 + (l&15)] = acc[i][j][r];
  __syncthreads();
  const int c0w = nt*128 + (w&1)*64;
  if (c0w < 192){
    const int cb = 24*h + (c0w>>3);
    const int mw = m0 + (w>>1)*64;
    u16* ob = out_sc + (long)b*12582912L + cb;
    const int nl0 = l>>3, sb = l&7;
#pragma unroll
    for (int ri=0; ri<8; ri++){
      int nl = ri*8 + nl0;
      const float* src = wb + nl*68 + sb;
      u32 d0 = (u32)f2bf(src[0])  | ((u32)f2bf(src[8])  << 16);
      u32 d1 = (u32)f2bf(src[16]) | ((u32)f2bf(src[24]) << 16);
      u32 d2 = (u32)f2bf(src[32]) | ((u32)f2bf(src[40]) << 16);
      u32 d3 = (u32)f2bf(src[48]) | ((u32)f2bf(src[56]) << 16);
      *(uint4*)(ob + ((long)sb*8192 + mw + nl)*192) = make_uint4(d0,d1,d2,d3);
    }
  }
}

extern "C" void kernel_launch(void* const* d_in, const int* in_sizes, int n_in,
                              void* d_out, int out_size, void* d_ws, size_t ws_size,
                              hipStream_t stream)
{
  const float* x      = (const float*)d_in[0];
  const float* qkv_w  = (const float*)d_in[1];
  const float* dw_w   = (const float*)d_in[2];
  const float* proj_w = (const float*)d_in[3];
  const float* temp   = (const float*)d_in[4];
  float* out = (float*)d_out;

  // workspace layout. qkv_raw occupies [150994944, 301989888) and is live
  // until dwconv completes; VT/out_sc/part/attn reuse that range only AFTER
  // it is dead. wq/wp/norms are live across the qkv GEMM -> placed PAST
  // 301989888 (this aliasing was the round-2/3 NaN bug). Total ~302.3 MB.
  char* ws = (char*)d_ws;
  u16*   xT      = (u16*)(ws + 0);             // [2][65536][192] bf16 (dies before conv written)
  u16*   conv    = (u16*)(ws + 0);             // [2][576][65536] bf16
  u16*   qkv_raw = (u16*)(ws + 150994944);     // [2][576][65536] bf16 (dies after dwconv)
  u16*   VT      = (u16*)(ws + 150994944);     // [16][8192][192] bf16 (over dead qkv_raw)
  u16*   out_sc  = (u16*)(ws + 201326592);     // [2][65536][192] bf16 (over dead qkv_raw)
  float* part    = (float*)(ws + 251658240);   // [128][192][192] f32  (over dead qkv_raw)
  u16*   attn    = (u16*)(ws + 270532608);     // [16][192][192] bf16  (over dead qkv_raw)
  u16*   wq_bf   = (u16*)(ws + 301989888);     // 576x192 bf16
  u16*   wp_bf   = (u16*)(ws + 302211072);     // 192x192 bf16
  float* norms   = (float*)(ws + 302284800);   // [1152][8] f32 sums of squares

  hipMemsetAsync(norms, 0, 9216*sizeof(float), stream);

  cvt_kernel<<<dim3(432), 256, 0, stream>>>(qkv_w, wq_bf, 110592);
  cvt_kernel<<<dim3(144), 256, 0, stream>>>(proj_w, wp_bf, 36864);

  // xT[b][s][c] = x[b][c][s]
  transpose_kernel<float><<<dim3(1024, 3, 2), 256, 0, stream>>>(
      x, xT, 0L, 12582912L, 12582912L, 65536);

  // qkv_raw = qkv_w @ x  (NT vs xT), M=576
  gemm_nt_kernel<u16><<<dim3(5, 512, 2), 256, 0, stream>>>(
      wq_bf, xT, qkv_raw, 576, 12582912L, 37748736L);

  // depthwise 3x3 + q/k row sum-of-squares
  dwconv_kernel<<<dim3(1152*16), 256, 0, stream>>>(qkv_raw, dw_w, conv, norms);

  // VT[bh][n][d] = Vslab[d][n]
  transpose_kernel<u16><<<dim3(128, 3, 16), 256, 0, stream>>>(
      conv + 25165824L, VT, 37748736L, 1572864L, 1572864L, 8192);

  // raw QK^T partials
  gemm_qk_kernel<<<dim3(3, 3, 128), 256, 0, stream>>>(conv, part);

  // reduce + normalize + temperature + softmax -> attn (bf16)
  softmax_kernel<<<dim3(3072), 64, 0, stream>>>(part, temp, norms, attn);

  // attn @ V -> out_sc [b][s][C]
  gemm_av_kernel<<<dim3(64, 2, 16), 256, 0, stream>>>(VT, attn, out_sc);

  // out = proj_w @ attn_out (NT vs out_sc), M=192, fp32 out
  gemm_nt_kernel<float><<<dim3(2, 512, 2), 256, 0, stream>>>(
      wp_bf, out_sc, out, 192, 12582912L, 12582912L);
}

// Round 5
// 452.855 us; speedup vs baseline: 2.2215x; 1.0107x over previous
//
#include <hip/hip_runtime.h>
#include <math.h>

typedef unsigned short u16;
typedef unsigned int   u32;
typedef short bf16x8 __attribute__((ext_vector_type(8)));
typedef float f32x4  __attribute__((ext_vector_type(4)));

#define MFMA16(a,b,c) __builtin_amdgcn_mfma_f32_16x16x32_bf16((a),(b),(c),0,0,0)

__device__ __forceinline__ float bf2f(u16 h){ u32 u=((u32)h)<<16; return __uint_as_float(u); }
__device__ __forceinline__ u16 f2bf(float f){ u32 u=__float_as_uint(f); return (u16)((u+0x7fffu+((u>>16)&1u))>>16); }

// async global->LDS, 16B/lane. LDS dest is wave-uniform base + lane*16 (m97 pattern).
__device__ __forceinline__ void gl2lds(const u16* g, u16* l){
  __builtin_amdgcn_global_load_lds((const __attribute__((address_space(1))) u32*)g,
                                   (__attribute__((address_space(3))) u32*)l, 16, 0, 0);
}
__device__ __forceinline__ void stc(u16* p, float v){ *p = f2bf(v); }
__device__ __forceinline__ void stc(float* p, float v){ *p = v; }
__device__ __forceinline__ void ld4(const float* p, float* v){ float4 x=*(const float4*)p; v[0]=x.x;v[1]=x.y;v[2]=x.z;v[3]=x.w; }
__device__ __forceinline__ void ld4(const u16* p, float* v){ ushort4 x=*(const ushort4*)p; v[0]=bf2f(x.x);v[1]=bf2f(x.y);v[2]=bf2f(x.z);v[3]=bf2f(x.w); }

// ---- prep: cvt weights to bf16 + zero norms (one dispatch) ----
__global__ void prep_kernel(const float* __restrict__ qkv_w, const float* __restrict__ proj_w,
                            u16* __restrict__ wq, u16* __restrict__ wp, float* __restrict__ norms){
  int i = blockIdx.x*256 + threadIdx.x;
  if (i < 110592) wq[i] = f2bf(qkv_w[i]);
  else if (i < 147456) wp[i-110592] = f2bf(proj_w[i-110592]);
  else if (i < 156672) norms[i-147456] = 0.f;
}

// ---- tiled transpose: in [z][192][in_pitch] (TIN) -> out [z][cols][192] bf16 ----
template<typename TIN>
__global__ __launch_bounds__(256) void transpose_kernel(
    const TIN* __restrict__ in, u16* __restrict__ out,
    long in_hi, long in_lo, long out_slab, int in_pitch)
{
  __shared__ float tile[64][65];
  const int t = threadIdx.x;
  const int z = blockIdx.z;
  const TIN* ip = in + (long)(z>>3)*in_hi + (long)(z&7)*in_lo;
  u16* op = out + (long)z*out_slab;
  const int s0 = blockIdx.x*64, c0 = blockIdx.y*64;
  const int rl = t>>4, cc = (t&15)*4;
#pragma unroll
  for (int rr=0; rr<4; rr++){
    int row = rr*16 + rl;
    float v[4];
    ld4(ip + (long)(c0+row)*in_pitch + s0 + cc, v);
    tile[row][cc+0]=v[0]; tile[row][cc+1]=v[1]; tile[row][cc+2]=v[2]; tile[row][cc+3]=v[3];
  }
  __syncthreads();
#pragma unroll
  for (int wr=0; wr<4; wr++){
    int sl = wr*16 + rl;
    ushort4 s;
    s.x = f2bf(tile[cc+0][sl]); s.y = f2bf(tile[cc+1][sl]);
    s.z = f2bf(tile[cc+2][sl]); s.w = f2bf(tile[cc+3][sl]);
    *(ushort4*)(op + (long)(s0+sl)*192 + c0 + cc) = s;
  }
}

// ---- NT MFMA GEMM: C[m][n] = sum_k A[m][k]*B[n][k]; K=192, lda=ldb=192, ldc=65536
template<typename TC>
__global__ __launch_bounds__(256) void gemm_nt_kernel(
    const u16* __restrict__ A, const u16* __restrict__ B, TC* __restrict__ C,
    int M, long sB, long sC)
{
  __shared__ __align__(16) u16 As[128*32];
  __shared__ __align__(16) u16 Bs[128*32];
  const int t = threadIdx.x, w = t>>6, l = t&63;
  const int mt = blockIdx.x, nt = blockIdx.y, bz = blockIdx.z;
  const int m0 = mt*128, n0 = nt*128;
  const u16* Bb = B + (long)bz*sB + (long)n0*192;
  const int rq = t>>2, qq = (t&3)*8;
  int ar0 = m0 + rq;      if (ar0 >= M) ar0 = M-1;
  int ar1 = m0 + 64 + rq; if (ar1 >= M) ar1 = M-1;
  f32x4 acc[4][4];
#pragma unroll
  for (int i=0;i<4;i++)
#pragma unroll
    for (int j=0;j<4;j++) acc[i][j] = f32x4{0.f,0.f,0.f,0.f};

  for (int k0=0; k0<192; k0+=32){
    __syncthreads();
    gl2lds(A + (long)ar0*192 + k0 + qq, As + t*8);
    gl2lds(A + (long)ar1*192 + k0 + qq, As + (256+t)*8);
    gl2lds(Bb + (long)rq*192 + k0 + qq, Bs + t*8);
    gl2lds(Bb + (long)(64+rq)*192 + k0 + qq, Bs + (256+t)*8);
    __syncthreads();
    const u16* ap = As + ((w>>1)*64 + (l&15))*32 + (l>>4)*8;
    const u16* bp = Bs + ((w&1)*64 + (l&15))*32 + (l>>4)*8;
    bf16x8 a[4], b[4];
#pragma unroll
    for (int i=0;i<4;i++){ a[i] = *(const bf16x8*)(ap + i*512); b[i] = *(const bf16x8*)(bp + i*512); }
#pragma unroll
    for (int i=0;i<4;i++)
#pragma unroll
      for (int j=0;j<4;j++) acc[i][j] = MFMA16(a[i], b[j], acc[i][j]);
  }
  const int mw = m0 + (w>>1)*64, nw = n0 + (w&1)*64;
  TC* Cb = C + (long)bz*sC;
#pragma unroll
  for (int i=0;i<4;i++){
#pragma unroll
    for (int r=0;r<4;r++){
      int row = mw + i*16 + (l>>4)*4 + r;
      if (row < M){
        TC* cp = Cb + (long)row*65536 + nw + (l&15);
#pragma unroll
        for (int j=0;j<4;j++) stc(cp + j*16, acc[i][j][r]);
      }
    }
  }
}

// ---- depthwise 3x3 + fused sum-of-squares. Thread = 4x4 output patch.
// LDS tile fp32 [18][264]: col 4..259 = image cols 0..255, cols 0..3/260..263 zero.
__global__ __launch_bounds__(256) void dwconv_kernel(
    const u16* __restrict__ in, const float* __restrict__ w9s,
    u16* __restrict__ out, float* __restrict__ norms)
{
  const int bo = blockIdx.x >> 4;
  const int rt = blockIdx.x & 15;
  const int o  = bo % 576;
  const u16* ip = in + (long)bo*65536L;
  u16* op = out + (long)bo*65536L;
  float w[9];
#pragma unroll
  for (int i=0;i<9;i++) w[i] = w9s[o*9+i];
  __shared__ float tile[18*264];
  const int t = threadIdx.x;
  if (t < 144){
    int row = t >> 3, c = t & 7;
    tile[row*264 + ((c<4) ? c : 256+c)] = 0.f;
  }
  for (int vi=t; vi<1152; vi+=256){
    int row = vi>>6, col = (vi&63)<<2;
    int g = rt*16 - 1 + row;
    float4 f;
    if (g >= 0 && g < 256){
      ushort4 u = *(const ushort4*)(ip + g*256 + col);
      f = make_float4(bf2f(u.x), bf2f(u.y), bf2f(u.z), bf2f(u.w));
    } else f = make_float4(0.f,0.f,0.f,0.f);
    *(float4*)&tile[row*264 + 4 + col] = f;
  }
  __syncthreads();
  const int tx = t & 63, ty = t >> 6;
  const float* base = &tile[4 + tx*4];
  float acc[4][4];
#pragma unroll
  for (int i=0;i<4;i++)
#pragma unroll
    for (int j=0;j<4;j++) acc[i][j] = 0.f;
#pragma unroll
  for (int r=0; r<6; r++){
    const float* row = base + (ty*4 + r)*264;
    float4 L = *(const float4*)(row - 4);
    float4 M = *(const float4*)(row);
    float4 R = *(const float4*)(row + 4);
    const float lf=L.w, m0=M.x, m1=M.y, m2=M.z, m3=M.w, rg=R.x;
#pragma unroll
    for (int ro=0; ro<4; ro++){
      if (r-ro >= 0 && r-ro <= 2){
        const int wr = (r-ro)*3;
        acc[ro][0] = fmaf(w[wr],lf, fmaf(w[wr+1],m0, fmaf(w[wr+2],m1, acc[ro][0])));
        acc[ro][1] = fmaf(w[wr],m0, fmaf(w[wr+1],m1, fmaf(w[wr+2],m2, acc[ro][1])));
        acc[ro][2] = fmaf(w[wr],m1, fmaf(w[wr+1],m2, fmaf(w[wr+2],m3, acc[ro][2])));
        acc[ro][3] = fmaf(w[wr],m2, fmaf(w[wr+1],m3, fmaf(w[wr+2],rg, acc[ro][3])));
      }
    }
  }
  float ss = 0.f;
#pragma unroll
  for (int ro=0; ro<4; ro++){
    ushort4 s;
    s.x = f2bf(acc[ro][0]); s.y = f2bf(acc[ro][1]);
    s.z = f2bf(acc[ro][2]); s.w = f2bf(acc[ro][3]);
    *(ushort4*)(op + (rt*16 + ty*4 + ro)*256 + tx*4) = s;
#pragma unroll
    for (int j=0;j<4;j++) ss = fmaf(acc[ro][j], acc[ro][j], ss);
  }
#pragma unroll
  for (int off=32; off>=1; off>>=1) ss += __shfl_xor(ss, off);
  __shared__ float red[4];
  if ((t&63)==0) red[t>>6] = ss;
  __syncthreads();
  if (t==0 && o < 384){
    atomicAdd(&norms[bo*8 + (rt>>1)], red[0]+red[1]+red[2]+red[3]);
  }
}

// ---- QK^T MFMA, K-split partials ----
__global__ __launch_bounds__(256) void gemm_qk_kernel(
    const u16* __restrict__ conv, float* __restrict__ part)
{
  __shared__ __align__(16) u16 As[64*64];
  __shared__ __align__(16) u16 Bs[64*64];
  const int t = threadIdx.x, w = t>>6, l = t&63;
  const int mt = blockIdx.x, nt = blockIdx.y, z = blockIdx.z;
  const int bh = z>>3, sl = z&7;
  const int b = bh>>3, h = bh&7;
  const u16* Q  = conv + (long)b*37748736L + (long)h*1572864L;
  const u16* Kp = Q + 12582912L;
  const int m0 = mt*64, n0 = nt*64;
  const int rq = t>>3, qq = (t&7)*8;
  const long qo0 = (long)(m0+rq)*8192 + qq;
  const long qo1 = (long)(m0+32+rq)*8192 + qq;
  const long ko0 = (long)(n0+rq)*8192 + qq;
  const long ko1 = (long)(n0+32+rq)*8192 + qq;
  f32x4 acc[2][2];
#pragma unroll
  for (int i=0;i<2;i++)
#pragma unroll
    for (int j=0;j<2;j++) acc[i][j] = f32x4{0.f,0.f,0.f,0.f};
  const int kbeg = sl*1024;
  for (int k0=kbeg; k0<kbeg+1024; k0+=64){
    __syncthreads();
    gl2lds(Q  + qo0 + k0, As + t*8);
    gl2lds(Q  + qo1 + k0, As + (256+t)*8);
    gl2lds(Kp + ko0 + k0, Bs + t*8);
    gl2lds(Kp + ko1 + k0, Bs + (256+t)*8);
    __syncthreads();
    const u16* ap = As + ((w>>1)*32 + (l&15))*64 + (l>>4)*8;
    const u16* bp = Bs + ((w&1)*32 + (l&15))*64 + (l>>4)*8;
#pragma unroll
    for (int ks=0; ks<2; ks++){
      bf16x8 a0 = *(const bf16x8*)(ap + ks*32);
      bf16x8 a1 = *(const bf16x8*)(ap + 1024 + ks*32);
      bf16x8 b0 = *(const bf16x8*)(bp + ks*32);
      bf16x8 b1 = *(const bf16x8*)(bp + 1024 + ks*32);
      acc[0][0]=MFMA16(a0,b0,acc[0][0]); acc[0][1]=MFMA16(a0,b1,acc[0][1]);
      acc[1][0]=MFMA16(a1,b0,acc[1][0]); acc[1][1]=MFMA16(a1,b1,acc[1][1]);
    }
  }
  float* P = part + (long)z*36864L;
  const int mw = m0 + (w>>1)*32, nw = n0 + (w&1)*32;
#pragma unroll
  for (int i=0;i<2;i++)
#pragma unroll
    for (int j=0;j<2;j++)
#pragma unroll
      for (int r=0;r<4;r++)
        P[(long)(mw + i*16 + (l>>4)*4 + r)*192 + nw + j*16 + (l&15)] = acc[i][j][r];
}

// ---- reduce partials + l2norm scales + temperature + softmax -> attn bf16 ----
__global__ __launch_bounds__(64) void softmax_kernel(
    const float* __restrict__ part, const float* __restrict__ temp,
    const float* __restrict__ norms, u16* __restrict__ attn)
{
  const int rg = blockIdx.x;
  const int bh = rg/192, r = rg - bh*192;
  const int b = bh>>3, h = bh&7;
  const int t = threadIdx.x;
  const float tp = temp[h];
  const float sq = norms[(b*576 + 24*h + (r>>3))*8 + (r&7)];
  const float invq = 1.f/fmaxf(sqrtf(sq), 1e-12f);
  const float* P = part + (long)bh*8L*36864L + (long)r*192;
  float lv[3];
#pragma unroll
  for (int j=0;j<3;j++){
    int col = t + j*64;
    float s = 0.f;
#pragma unroll
    for (int ks=0; ks<8; ks++) s += P[(long)ks*36864L + col];
    float sk = norms[(b*576 + 192 + 24*h + (col>>3))*8 + (col&7)];
    float invk = 1.f/fmaxf(sqrtf(sk), 1e-12f);
    lv[j] = s*invq*invk*tp;
  }
  float mx = fmaxf(lv[0], fmaxf(lv[1], lv[2]));
#pragma unroll
  for (int o=32;o>=1;o>>=1) mx = fmaxf(mx, __shfl_xor(mx, o));
  float e[3], sum = 0.f;
#pragma unroll
  for (int j=0;j<3;j++){ e[j] = expf(lv[j]-mx); sum += e[j]; }
#pragma unroll
  for (int o=32;o>=1;o>>=1) sum += __shfl_xor(sum, o);
  const float inv = 1.f/sum;
  u16* ap = attn + (long)bh*36864L + (long)r*192;
#pragma unroll
  for (int j=0;j<3;j++) ap[t + j*64] = f2bf(e[j]*inv);
}

// ---- attn@V with LDS-bounce epilogue -> out_sc[s][C] ----
__global__ __launch_bounds__(256) void gemm_av_kernel(
    const u16* __restrict__ VT, const u16* __restrict__ attn, u16* __restrict__ out_sc)
{
  __shared__ __align__(16) char smem[69632];
  u16* As = (u16*)smem;
  u16* Bs = (u16*)(smem + 8192);
  const int t = threadIdx.x, w = t>>6, l = t&63;
  const int mt = blockIdx.x, nt = blockIdx.y, bh = blockIdx.z;
  const int b = bh>>3, h = bh&7;
  const u16* Av = VT + (long)bh*1572864L;
  const u16* Bt = attn + (long)bh*36864L;
  const int m0 = mt*128, n0 = nt*128;
  const int rq = t>>2, qq = (t&3)*8;
  int br0 = n0 + rq;      if (br0 > 191) br0 = 191;
  int br1 = n0 + 64 + rq; if (br1 > 191) br1 = 191;
  f32x4 acc[4][4];
#pragma unroll
  for (int i=0;i<4;i++)
#pragma unroll
    for (int j=0;j<4;j++) acc[i][j] = f32x4{0.f,0.f,0.f,0.f};
  for (int k0=0; k0<192; k0+=32){
    __syncthreads();
    gl2lds(Av + (long)(m0+rq)*192 + k0 + qq, As + t*8);
    gl2lds(Av + (long)(m0+64+rq)*192 + k0 + qq, As + (256+t)*8);
    gl2lds(Bt + (long)br0*192 + k0 + qq, Bs + t*8);
    gl2lds(Bt + (long)br1*192 + k0 + qq, Bs + (256+t)*8);
    __syncthreads();
    const u16* ap = As + ((w>>1)*64 + (l&15))*32 + (l>>4)*8;
    const u16* bp = Bs + ((w&1)*64 + (l&15))*32 + (l>>4)*8;
    bf16x8 a[4], bb[4];
#pragma unroll
    for (int i=0;i<4;i++){ a[i] = *(const bf16x8*)(ap + i*512); bb[i] = *(const bf16x8*)(bp + i*512); }
#pragma unroll
    for (int i=0;i<4;i++)
#pragma unroll
      for (int j=0;j<4;j++) acc[i][j] = MFMA16(a[i], bb[j], acc[i][j]);
  }
  __syncthreads();
  float* wb = (float*)smem + w*4352;
#pragma unroll
  for (int i=0;i<4;i++)
#pragma unroll
    for (int j=0;j<4;j++)
#pragma unroll
      for (int r=0;r<4;r++)
        wb[(i*16 + (l>>4)*4 + r)*68 + j*16 + (l&15)] = acc[i][j][r];
  __syncthreads();
  const int c0w = nt*128 + (w&1)*64;
  if (c0w < 192){
    const int cb = 24*h + (c0w>>3);
    const int mw = m0 + (w>>1)*64;
    u16* ob = out_sc + (long)b*12582912L + cb;
    const int nl0 = l>>3, sb = l&7;
#pragma unroll
    for (int ri=0; ri<8; ri++){
      int nl = ri*8 + nl0;
      const float* src = wb + nl*68 + sb;
      u32 d0 = (u32)f2bf(src[0])  | ((u32)f2bf(src[8])  << 16);
      u32 d1 = (u32)f2bf(src[16]) | ((u32)f2bf(src[24]) << 16);
      u32 d2 = (u32)f2bf(src[32]) | ((u32)f2bf(src[40]) << 16);
      u32 d3 = (u32)f2bf(src[48]) | ((u32)f2bf(src[56]) << 16);
      *(uint4*)(ob + ((long)sb*8192 + mw + nl)*192) = make_uint4(d0,d1,d2,d3);
    }
  }
}

extern "C" void kernel_launch(void* const* d_in, const int* in_sizes, int n_in,
                              void* d_out, int out_size, void* d_ws, size_t ws_size,
                              hipStream_t stream)
{
  const float* x      = (const float*)d_in[0];
  const float* qkv_w  = (const float*)d_in[1];
  const float* dw_w   = (const float*)d_in[2];
  const float* proj_w = (const float*)d_in[3];
  const float* temp   = (const float*)d_in[4];
  float* out = (float*)d_out;

  // workspace layout. qkv_raw live in [150994944, 301989888) until dwconv done;
  // VT/out_sc/part/attn reuse that range after. wq/wp/norms live across the qkv
  // GEMM -> placed PAST 301989888 (aliasing here was the round-2/3 NaN bug).
  char* ws = (char*)d_ws;
  u16*   xT      = (u16*)(ws + 0);
  u16*   conv    = (u16*)(ws + 0);
  u16*   qkv_raw = (u16*)(ws + 150994944);
  u16*   VT      = (u16*)(ws + 150994944);
  u16*   out_sc  = (u16*)(ws + 201326592);
  float* part    = (float*)(ws + 251658240);
  u16*   attn    = (u16*)(ws + 270532608);
  u16*   wq_bf   = (u16*)(ws + 301989888);
  u16*   wp_bf   = (u16*)(ws + 302211072);
  float* norms   = (float*)(ws + 302284800);

  prep_kernel<<<dim3(612), 256, 0, stream>>>(qkv_w, proj_w, wq_bf, wp_bf, norms);

  // xT[b][s][c] = x[b][c][s]
  transpose_kernel<float><<<dim3(1024, 3, 2), 256, 0, stream>>>(
      x, xT, 0L, 12582912L, 12582912L, 65536);

  // qkv_raw = qkv_w @ x  (NT vs xT), M=576
  gemm_nt_kernel<u16><<<dim3(5, 512, 2), 256, 0, stream>>>(
      wq_bf, xT, qkv_raw, 576, 12582912L, 37748736L);

  // depthwise 3x3 + q/k sum-of-squares
  dwconv_kernel<<<dim3(1152*16), 256, 0, stream>>>(qkv_raw, dw_w, conv, norms);

  // VT[bh][n][d] = Vslab[d][n]
  transpose_kernel<u16><<<dim3(128, 3, 16), 256, 0, stream>>>(
      conv + 25165824L, VT, 37748736L, 1572864L, 1572864L, 8192);

  // raw QK^T partials
  gemm_qk_kernel<<<dim3(3, 3, 128), 256, 0, stream>>>(conv, part);

  // reduce + normalize + temperature + softmax -> attn (bf16)
  softmax_kernel<<<dim3(3072), 64, 0, stream>>>(part, temp, norms, attn);

  // attn @ V -> out_sc [b][s][C]
  gemm_av_kernel<<<dim3(64, 2, 16), 256, 0, stream>>>(VT, attn, out_sc);

  // out = proj_w @ attn_out (NT vs out_sc), M=192, fp32 out
  gemm_nt_kernel<float><<<dim3(2, 512, 2), 256, 0, stream>>>(
      wp_bf, out_sc, out, 192, 12582912L, 12582912L);
}